// Round 21
// baseline (66.319 us; speedup 1.0000x reference)
//
#include <hip/hip_runtime.h>

#pragma clang fp contract(off)

#define N_PTS   16384
#define N_SEEDS 20
#define KP1     11      // K+1, K=10
#define NBIN    512     // bits(d2) >> 22 : exponent + 1 mantissa bit
#define NREP    32      // hist[bin*32 + (t&31)] -> bank == t&31 (conflict-free)
#define CAP     4096    // candidate buffer; also LDS pad: >80KB total -> 1 block/CU
#define NKNN    3       // knn-role blocks per batch

typedef unsigned long long u64;
typedef unsigned int       u32;

// DPP fmax step: m = fmax(m, dpp_select(m)). VALU pipe (~5cyc) vs ds_swizzle.
#define FMAXDPP(m, ctrl, rmask) { \
    const int _v = __builtin_amdgcn_update_dpp(__float_as_int(m), __float_as_int(m), \
                                               (ctrl), (rmask), 0xf, false); \
    m = fmaxf(m, __int_as_float(_v)); }

#define FDECL(i) float px##i, py##i, pz##i, dd##i = 1e10f;

// load 4 consecutive points (group a) from 3 float4s at P4[f4 + 3a ...]
#define LDGRP(a, i0, i1, i2, i3) { \
    const float4 qa = P4[f4 + 3*(a)], qb = P4[f4 + 3*(a)+1], qc = P4[f4 + 3*(a)+2]; \
    px##i0 = qa.x; py##i0 = qa.y; pz##i0 = qa.z; \
    px##i1 = qa.w; py##i1 = qb.x; pz##i1 = qb.y; \
    px##i2 = qb.z; py##i2 = qb.w; pz##i2 = qc.x; \
    px##i3 = qc.y; py##i3 = qc.z; pz##i3 = qc.w; }

#define DECL32 \
    FDECL(0)  FDECL(1)  FDECL(2)  FDECL(3)  FDECL(4)  FDECL(5)  FDECL(6)  FDECL(7) \
    FDECL(8)  FDECL(9)  FDECL(10) FDECL(11) FDECL(12) FDECL(13) FDECL(14) FDECL(15) \
    FDECL(16) FDECL(17) FDECL(18) FDECL(19) FDECL(20) FDECL(21) FDECL(22) FDECL(23) \
    FDECL(24) FDECL(25) FDECL(26) FDECL(27) FDECL(28) FDECL(29) FDECL(30) FDECL(31)

#define LOAD32 { const int f4 = t * 24; \
    LDGRP(0, 0, 1, 2, 3)    LDGRP(1, 4, 5, 6, 7) \
    LDGRP(2, 8, 9, 10, 11)  LDGRP(3, 12, 13, 14, 15) \
    LDGRP(4, 16, 17, 18, 19) LDGRP(5, 20, 21, 22, 23) \
    LDGRP(6, 24, 25, 26, 27) LDGRP(7, 28, 29, 30, 31) }

// ---------------------------------------------------------------------------
// 256 blocks x 512 threads (8 waves), ~84KB LDS -> 1 block/CU on 256 CUs.
// KEY CHANGE vs r20: 512-thread blocks + waves_per_eu(2,2) -> 256 arch-VGPR
// budget per wave -> the 32-pt/thread coord+dd state (128 floats) lives in
// ARCH VGPRs with no AGPR round-trips (at 1024 thr the 64-VGPR cap forced
// v_accvgpr traffic on every FSTEP access - the hidden ~2x issue tax).
// All value-level logic is bitwise-identical to r20 (indexless fmax chains
// are order-invariant; scan/ballot first-index tie-breaks unchanged).
//   bid <  B : FPS (indexless FSTEP, DPP reduce, post-hoc index recovery).
//   bid >= B : kNN radix-select; RELAXED seed poll; fence + done-add.
//   bid == B : polls done==NKNN*B-1 (init -1), fences, stats in-kernel.
// ---------------------------------------------------------------------------
__global__ __launch_bounds__(512)
__attribute__((amdgpu_waves_per_eu(2, 2)))
void fused_kernel(const float* __restrict__ pcs,
                  int* __restrict__ seeds,
                  int* __restrict__ done,
                  float* __restrict__ topd,
                  float* __restrict__ out,
                  int B) {
    __shared__ alignas(16) u32 hist[NBIN * NREP];   // 64 KB (knn) / f64 scratch (stats)
    __shared__ u32    part[NBIN];
    __shared__ float  cand[CAP];                    // 16 KB (also the >80KB pad)
    __shared__ u32    cnt;
    __shared__ u32    s_thr;
    __shared__ int    s_sid;
    __shared__ float  s_val[2][8];                  // fps: 8 wave maxima
    __shared__ float4 s_pack[2];                    // fps: {idx_bits, cx, cy, cz}

    const int bid  = blockIdx.x;
    const int t    = threadIdx.x;
    const int lane = t & 63;
    const int wid  = t >> 6;

    if (bid < B) {
        // ================= FPS role =================
        const float* __restrict__ P  = pcs + (size_t)bid * N_PTS * 3;
        const float4* __restrict__ P4 = (const float4*)P;

        DECL32
        LOAD32

        float cx = P[0], cy = P[1], cz = P[2];
        int farthest = 0;

        for (int it = 0; it < N_SEEDS; ++it) {
            if (t == 0)    // RELAXED: value-only payload (r9-proven)
                __hip_atomic_store(&seeds[bid * N_SEEDS + it], farthest,
                                   __ATOMIC_RELAXED, __HIP_MEMORY_SCOPE_AGENT);
            if (it == N_SEEDS - 1) break;   // last argmax discarded by scan

            // ---- indexless FSTEP: 4 independent value-only max chains -----
            float v0 = -1.f, v1 = -1.f, v2 = -1.f, v3 = -1.f;
#define FS(c, i) { const float dx = px##i - cx, dy = py##i - cy, dz = pz##i - cz; \
        const float d  = (dx*dx + dy*dy) + dz*dz; \
        const float nd = fminf(dd##i, d); dd##i = nd; \
        v##c = fmaxf(v##c, nd); }
            FS(0,0)  FS(1,1)  FS(2,2)  FS(3,3)
            FS(0,4)  FS(1,5)  FS(2,6)  FS(3,7)
            FS(0,8)  FS(1,9)  FS(2,10) FS(3,11)
            FS(0,12) FS(1,13) FS(2,14) FS(3,15)
            FS(0,16) FS(1,17) FS(2,18) FS(3,19)
            FS(0,20) FS(1,21) FS(2,22) FS(3,23)
            FS(0,24) FS(1,25) FS(2,26) FS(3,27)
            FS(0,28) FS(1,29) FS(2,30) FS(3,31)
            const float bestv = fmaxf(fmaxf(v0, v1), fmaxf(v2, v3));

            // ---- stage 1: wave max via DPP --------------------------------
            float m = bestv;
            FMAXDPP(m, 0x111, 0xf)   // row_shr:1
            FMAXDPP(m, 0x112, 0xf)   // row_shr:2
            FMAXDPP(m, 0x114, 0xf)   // row_shr:4
            FMAXDPP(m, 0x118, 0xf)   // row_shr:8
            FMAXDPP(m, 0x142, 0xa)   // row_bcast:15
            FMAXDPP(m, 0x143, 0xc)   // row_bcast:31; lane63 = wave max
            const float wmax = __int_as_float(
                __builtin_amdgcn_readlane(__float_as_int(m), 63));
            const int par = it & 1;
            if (lane == 0) s_val[par][wid] = wmax;
            __syncthreads();                 // B1: 8 wave maxima in LDS

            // ---- stage 2: block max over 8; winner recovers index ---------
            const float v8 = s_val[par][lane & 7];
            float r = v8;
            FMAXDPP(r, 0x111, 0xf)
            FMAXDPP(r, 0x112, 0xf)
            FMAXDPP(r, 0x114, 0xf)   // lane7 = max of the 8
            const float gmax = __int_as_float(
                __builtin_amdgcn_readlane(__float_as_int(r), 7));
            const u64 m2 = __ballot(v8 == gmax) & 0xFFull;
            const int ws = __ffsll((unsigned long long)m2) - 1;

            if (wid == ws) {                 // winning wave only
                const u64 lm = __ballot(bestv == gmax);
                const int ll = __ffsll((unsigned long long)lm) - 1;
                if (lane == ll) {            // winning lane: descending scan
                    int fi = 0; float sx = 0.f, sy = 0.f, sz = 0.f;
#define SCAN(i) if (dd##i == gmax) { fi = t*32 + (i); sx = px##i; sy = py##i; sz = pz##i; }
                    SCAN(31) SCAN(30) SCAN(29) SCAN(28)
                    SCAN(27) SCAN(26) SCAN(25) SCAN(24)
                    SCAN(23) SCAN(22) SCAN(21) SCAN(20)
                    SCAN(19) SCAN(18) SCAN(17) SCAN(16)
                    SCAN(15) SCAN(14) SCAN(13) SCAN(12)
                    SCAN(11) SCAN(10) SCAN(9)  SCAN(8)
                    SCAN(7)  SCAN(6)  SCAN(5)  SCAN(4)
                    SCAN(3)  SCAN(2)  SCAN(1)  SCAN(0)
                    s_pack[par] = make_float4(__int_as_float(fi), sx, sy, sz);
                }
            }
            __syncthreads();                 // B2: winner published

            const float4 pk = s_pack[par];
            farthest = __float_as_int(pk.x);
            cx = pk.y; cy = pk.z; cz = pk.w;
        }
    } else {
        // ================= kNN-select role =================
        const int kk = bid - B;
        const int b  = kk % B;          // bid ≡ b (mod 8): same XCD as fps block
        const int j  = kk / B;

        const float* __restrict__ P  = pcs + (size_t)b * N_PTS * 3;
        const float4* __restrict__ P4 = (const float4*)P;
        const int rep = t & 31;

        DECL32
        LOAD32             // dd regs unused -> DCE'd

#pragma unroll
        for (int i = 0; i < (NBIN * NREP) / 512; ++i) hist[t + i * 512] = 0u;
        if (t == 0) cnt = 0u;

        for (int s = j; s < N_SEEDS; s += NKNN) {
            if (t == 0) {   // RELAXED poll: seed index is the whole payload
                int sv;
                while ((sv = __hip_atomic_load(&seeds[b * N_SEEDS + s],
                               __ATOMIC_RELAXED, __HIP_MEMORY_SCOPE_AGENT)) < 0)
                    __builtin_amdgcn_s_sleep(2);
                s_sid = sv;
            }
            __syncthreads();                  // B0: sid ready, hist+cnt zeroed
            const int sid = s_sid;
            const float cx = P[sid*3], cy = P[sid*3+1], cz = P[sid*3+2];

            // ---- histogram pass (d transient) -----------------------------
#define HSTEP(i) { const float dx = px##i - cx, dy = py##i - cy, dz = pz##i - cz; \
        const float d = fmaf(dz, dz, fmaf(dy, dy, dx * dx)); \
        atomicAdd(&hist[(__float_as_uint(d) >> 22) * NREP + rep], 1u); }
            HSTEP(0)  HSTEP(1)  HSTEP(2)  HSTEP(3)
            HSTEP(4)  HSTEP(5)  HSTEP(6)  HSTEP(7)
            HSTEP(8)  HSTEP(9)  HSTEP(10) HSTEP(11)
            HSTEP(12) HSTEP(13) HSTEP(14) HSTEP(15)
            HSTEP(16) HSTEP(17) HSTEP(18) HSTEP(19)
            HSTEP(20) HSTEP(21) HSTEP(22) HSTEP(23)
            HSTEP(24) HSTEP(25) HSTEP(26) HSTEP(27)
            HSTEP(28) HSTEP(29) HSTEP(30) HSTEP(31)
            __syncthreads();                  // B1: hist complete

            {   // fold 32 replicas per bin (t covers all 512 bins)
                u32 ssum = 0;
#pragma unroll
                for (int r2 = 0; r2 < NREP; ++r2)
                    ssum += hist[t * NREP + ((r2 + t) & (NREP - 1))];
                part[t] = ssum;
            }
            __syncthreads();                  // B2: part[] ready

            if (wid == 0) {
                u32 s8 = 0;
#pragma unroll
                for (int i = 0; i < 8; ++i)
                    s8 += part[lane * 8 + ((i + lane) & 7)];
                u32 cum = s8;
                for (int off = 1; off < 64; off <<= 1) {
                    const u32 o = __shfl_up(cum, off);
                    if (lane >= off) cum += o;
                }
                const u64 mm = __ballot(cum >= (u32)KP1);
                const int L  = __ffsll((unsigned long long)mm) - 1;
                const u32 below = __shfl(cum - s8, L);
                const u32 bc = (lane < 8) ? part[L * 8 + lane] : 0u;
                u32 ic = bc;
                for (int off = 1; off < 8; off <<= 1) {
                    const u32 o = __shfl_up(ic, off);
                    if (lane >= off) ic += o;
                }
                const u64 mm2 = __ballot(lane < 8 && (below + ic) >= (u32)KP1);
                const int l2  = __ffsll((unsigned long long)mm2) - 1;
                if (lane == 0) s_thr = (u32)(L * 8 + l2 + 1) << 22;
            } else {
                if (t == 64) cnt = 0u;        // reset for this seed's collect
                for (int i = t - 64; i < NBIN * NREP; i += 448) hist[i] = 0u;
            }
            __syncthreads();                  // B3: thr ready, hist zeroed, cnt=0

            // ---- collect candidates (recompute d: bitwise same as HSTEP) --
            const float thrf = __uint_as_float(s_thr);
#define CSTEP(i) { const float dx = px##i - cx, dy = py##i - cy, dz = pz##i - cz; \
        const float d = fmaf(dz, dz, fmaf(dy, dy, dx * dx)); \
        if (d < thrf) { const u32 sl = atomicAdd(&cnt, 1u); \
                        if (sl < (u32)CAP) cand[sl] = d; } }
            CSTEP(0)  CSTEP(1)  CSTEP(2)  CSTEP(3)
            CSTEP(4)  CSTEP(5)  CSTEP(6)  CSTEP(7)
            CSTEP(8)  CSTEP(9)  CSTEP(10) CSTEP(11)
            CSTEP(12) CSTEP(13) CSTEP(14) CSTEP(15)
            CSTEP(16) CSTEP(17) CSTEP(18) CSTEP(19)
            CSTEP(20) CSTEP(21) CSTEP(22) CSTEP(23)
            CSTEP(24) CSTEP(25) CSTEP(26) CSTEP(27)
            CSTEP(28) CSTEP(29) CSTEP(30) CSTEP(31)
            __syncthreads();                  // B4: candidates ready

            if (wid == 0) {
                const u32 n = min(cnt, (u32)CAP);
                for (u32 base = 0; base < n; base += 64) {
                    const u32 idx = base + (u32)lane;
                    const float vv = (idx < n) ? cand[idx] : 3.0e38f;
                    u32 r2 = 0;
                    for (u32 jj = 0; jj < n; ++jj) {
                        const float w = cand[jj];
                        r2 += (w < vv || (w == vv && jj < idx)) ? 1u : 0u;
                    }
                    if (idx < n && r2 < (u32)KP1)
                        topd[(b * N_SEEDS + s) * KP1 + r2] = sqrtf(vv);
                }
            }
        }

        // -------- signal completion (one fence per block, off hot path) ----
        __syncthreads();
        if (t == 0) {
            __threadfence();                  // make topd visible at agent scope
            __hip_atomic_fetch_add(done, 1, __ATOMIC_RELAXED,
                                   __HIP_MEMORY_SCOPE_AGENT);
        }

        // ================= stats role (block B only) =======================
        if (bid == B) {
            const int target = NKNN * B - 1;      // done init = -1 (0xFF memset)
            if (t == 0) {
                while (__hip_atomic_load(done, __ATOMIC_RELAXED,
                                         __HIP_MEMORY_SCOPE_AGENT) != target)
                    __builtin_amdgcn_s_sleep(8);
            }
            __syncthreads();
            __threadfence();    // acquire side: invalidate before topd reads

            const int pairs = B * N_SEEDS;
            const int total = pairs * KP1;
            double* red = (double*)hist;          // 4 KB scratch, hist is dead

            double s1 = 0.0;
            for (int i = t; i < total; i += 512)
                if (i % KP1 != 0) s1 += (double)topd[i];
            red[t] = s1;
            __syncthreads();
            for (int off = 256; off; off >>= 1) {
                if (t < off) red[t] += red[t + off];
                __syncthreads();
            }
            const double om = red[0] / (double)(pairs * (KP1 - 1));

            double sm = 0.0, sm2 = 0.0;
            for (int pr = t; pr < pairs; pr += 512) {
                double acc = 0.0;
                for (int jj = 0; jj < KP1; ++jj) acc += (double)topd[pr * KP1 + jj];
                const double m = acc / (om * (double)KP1);
                sm += m;
                sm2 += m * m;
            }
            __syncthreads();
            red[t] = sm;
            __syncthreads();
            for (int off = 256; off; off >>= 1) {
                if (t < off) red[t] += red[t + off];
                __syncthreads();
            }
            const double Sm = red[0];
            __syncthreads();
            red[t] = sm2;
            __syncthreads();
            for (int off = 256; off; off >>= 1) {
                if (t < off) red[t] += red[t + off];
                __syncthreads();
            }
            if (t == 0) {
                const double var = (red[0] - Sm * Sm / (double)pairs)
                                   / (double)(pairs - 1);
                out[0] = (float)var;
            }
        }
    }
}

// ---------------------------------------------------------------------------
extern "C" void kernel_launch(void* const* d_in, const int* in_sizes, int n_in,
                              void* d_out, int out_size, void* d_ws, size_t ws_size,
                              hipStream_t stream) {
    const float* pcs = (const float*)d_in[0];
    const int B = in_sizes[0] / (N_PTS * 3);

    int*   seeds = (int*)d_ws;                          // B*20 ints
    int*   done  = (int*)((char*)d_ws + 5120);          // 1 int, init -1
    float* topd  = (float*)((char*)d_ws + 8192);        // B*20*11 floats
    float* out   = (float*)d_out;

    // seeds -> -1, done -> -1 every launch (graph replays don't re-poison)
    (void)hipMemsetAsync(d_ws, 0xFF, 8192, stream);

    fused_kernel<<<B * (1 + NKNN), 512, 0, stream>>>(pcs, seeds, done, topd, out, B);
}